// Round 6
// baseline (2479.380 us; speedup 1.0000x reference)
//
#include <hip/hip_runtime.h>
#include <hip/hip_bf16.h>

#define B_DIM 128
#define T_DIM 512
#define I_DIMV 256
#define H_DIM 1024
#define G_DIM 4096
#define K_TOT 1280
#define C_DIM 1000
#define A_STRIDE 1288   // 1280 + 8 shorts pad (byte stride 2576, 16B aligned)

typedef __attribute__((ext_vector_type(8))) short short8;
typedef __attribute__((ext_vector_type(4))) float f32x4;
typedef __attribute__((ext_vector_type(4))) unsigned short ushort4v;
typedef __attribute__((ext_vector_type(4))) int int4v;

__device__ __forceinline__ unsigned short f2bf(float f) {
    unsigned int u = __float_as_uint(f);
    u += 0x7FFF + ((u >> 16) & 1);   // round-to-nearest-even
    return (unsigned short)(u >> 16);
}

__device__ __forceinline__ float sigmoid_f(float x) {
    return __builtin_amdgcn_rcpf(1.0f + __expf(-x));
}
__device__ __forceinline__ float tanh_f(float x) {
    return 1.0f - 2.0f * __builtin_amdgcn_rcpf(1.0f + __expf(2.0f * x));
}

// ---------------------------------------------------------------------------
// Prologue: combined bf16 weights (gate-interleaved rows p = j*4+q), bf16 x,
// combined bias, zeroed h0, zeroed barrier state (in d_out). Runs every call.
// ---------------------------------------------------------------------------
__global__ void prep_kernel(const float* __restrict__ x,
                            const float* __restrict__ Wih,
                            const float* __restrict__ Whh,
                            const float* __restrict__ bih,
                            const float* __restrict__ bhh,
                            unsigned short* __restrict__ Wc,
                            unsigned short* __restrict__ xbf,
                            float* __restrict__ biasc,
                            unsigned short* __restrict__ h0,
                            unsigned* __restrict__ bar)
{
    const int tid = blockIdx.x * blockDim.x + threadIdx.x;
    const int nth = gridDim.x * blockDim.x;

    const int WcN4 = G_DIM * K_TOT / 4;
    for (int i = tid; i < WcN4; i += nth) {
        int p = i / (K_TOT / 4);
        int k = (i - p * (K_TOT / 4)) * 4;
        int j = p >> 2, q = p & 3;
        int r = q * H_DIM + j;
        const float* src = (k < H_DIM) ? (Whh + (size_t)r * H_DIM + k)
                                       : (Wih + (size_t)r * I_DIMV + (k - H_DIM));
        f32x4 v = *(const f32x4*)src;
        ushort4v o;
        o.x = f2bf(v.x); o.y = f2bf(v.y); o.z = f2bf(v.z); o.w = f2bf(v.w);
        *(ushort4v*)(Wc + (size_t)i * 4) = o;
    }
    const int xN4 = B_DIM * T_DIM * I_DIMV / 4;
    for (int i = tid; i < xN4; i += nth) {
        f32x4 v = *(const f32x4*)(x + (size_t)i * 4);
        ushort4v o;
        o.x = f2bf(v.x); o.y = f2bf(v.y); o.z = f2bf(v.z); o.w = f2bf(v.w);
        *(ushort4v*)(xbf + (size_t)i * 4) = o;
    }
    for (int p = tid; p < G_DIM; p += nth) {
        int j = p >> 2, q = p & 3;
        int r = q * H_DIM + j;
        biasc[p] = bih[r] + bhh[r];
    }
    const int hN4 = B_DIM * H_DIM / 4;
    for (int i = tid; i < hN4; i += nth) {
        ushort4v z = {0, 0, 0, 0};
        *(ushort4v*)(h0 + (size_t)i * 4) = z;
    }
    for (int i = tid; i < 1024; i += nth) bar[i] = 0;
}

// ---------------------------------------------------------------------------
// Persistent LSTM, plain launch. 256 WGs x 256 threads; co-residency is
// structural (LDS 41KB, 1 WG/CU by VGPR budget; 256 WGs on 256 CUs -> all
// dispatched immediately).
// WG: m_blk = wgid>>5 -> batches [16*m_blk, +16) (= sync group)
//     n_blk = wgid&31 -> hidden [32*n_blk, +32) == gate rows [128*n_blk,+128)
// W slice in registers for all 512 steps. h exchanged MALL-direct (sc0 sc1).
// Sync: proven R3 rendezvous barrier, but SPLIT into ARRIVE (drain +
// fetch_add + last-arriver gen release) and WAIT (tid0 spin + sync). Between
// the two halves the WG stages x_{t+1} and computes its gate contribution
// (xacc, K-chunks 32..39) -- work that is independent of h_t and previously
// sat on the critical path. The h K-loop (chunks 0..31) then starts from
// xacc. Logical barrier placement is IDENTICAL to R3 (arrive at end of step
// t, wait at top of step t+1): skew <= 1 step, two h buffers suffice, and
// the counter-reset ordering argument (cnt=0 stored before gen release;
// arrival for epoch t+1 only after observing gen >= t) carries over.
// LDS regions: h cols [0,1024) and x cols [1024,1280) are disjoint; xacc
// reads of step t are separated from x-staging writes of step t+1 by the
// arrive __syncthreads, and x-staging writes from xacc reads by another
// __syncthreads. No new sync primitives, no probes.
// ---------------------------------------------------------------------------
__global__ __launch_bounds__(256, 1)
void lstm_grid(const unsigned short* __restrict__ Wc,
               const unsigned short* __restrict__ xbf,
               const float* __restrict__ biasc,
               unsigned short* __restrict__ hb0,
               unsigned short* __restrict__ hb1,
               float* __restrict__ hf32,
               unsigned* __restrict__ bar)
{
    __shared__ __align__(16) unsigned short Alds[16 * A_STRIDE];  // 41,216 B

    const int tid   = threadIdx.x;
    const int wgid  = blockIdx.x;
    const int m_blk = wgid >> 5;
    const int n_blk = wgid & 31;
    const int b0 = m_blk * 16;         // batch rows [b0, b0+16)
    const int p0 = n_blk * 128;        // gate rows  [p0, p0+128)
    const int j0 = n_blk * 32;         // hidden cols [j0, j0+32)

    const int wid  = tid >> 6;         // wave -> gate cols [wid*32, +32)
    const int lane = tid & 63;
    const int cl   = lane & 15;
    const int quad = lane >> 4;
    const int q_g  = cl & 3;           // gate: 0=i 1=f 2=g 3=o
    const int jl   = cl >> 2;

    const float bias0 = biasc[p0 + wid * 32 + cl];
    const float bias1 = biasc[p0 + wid * 32 + 16 + cl];

    // W slice in registers: 2 subtiles x 40 k-chunks = 80 x short8 (320 regs)
    // chunks 0..31 = h part (k 0..1023), chunks 32..39 = x part (k 1024..1279)
    short8 Wreg[80];
    {
        const unsigned short* w0 = Wc + (size_t)(p0 + wid * 32 + cl) * K_TOT + quad * 8;
        const unsigned short* w1 = w0 + (size_t)16 * K_TOT;
        #pragma unroll
        for (int c = 0; c < 40; ++c) {
            Wreg[c]      = *(const short8*)(w0 + c * 32);
            Wreg[40 + c] = *(const short8*)(w1 + c * 32);
        }
    }

    unsigned* const cnt = bar + 64 * m_blk;
    unsigned* const gen = bar + 64 * m_blk + 32;

    float c0v = 0.0f, c1v = 0.0f;      // cell state: 1 cell/lane per subtile

    // ---- prologue: stage x_0, compute xacc_0 ----
    f32x4 xacc0 = {0.f, 0.f, 0.f, 0.f};
    f32x4 xacc1 = {0.f, 0.f, 0.f, 0.f};
    {
        #pragma unroll
        for (int u = 0; u < 2; ++u) {
            const int idx = u * 256 + tid;          // 0..511
            const int row = idx >> 5;               // 0..15
            const int col = (idx & 31) * 8;         // 0..248
            short8 xv = *(const short8*)(xbf + (size_t)(b0 + row) * (T_DIM * I_DIMV)
                                         + col);
            *(short8*)(&Alds[row * A_STRIDE + 1024 + col]) = xv;
        }
        __syncthreads();
        #pragma unroll
        for (int c = 0; c < 8; ++c) {
            short8 a = *(const short8*)(&Alds[cl * A_STRIDE + 1024 + c * 32 + quad * 8]);
            xacc0 = __builtin_amdgcn_mfma_f32_16x16x32_bf16(a, Wreg[32 + c], xacc0, 0, 0, 0);
            xacc1 = __builtin_amdgcn_mfma_f32_16x16x32_bf16(a, Wreg[72 + c], xacc1, 0, 0, 0);
        }
    }

    for (int t = 0; t < T_DIM; ++t) {
        const unsigned short* hread = (t & 1) ? hb1 : hb0;
        unsigned short* hwrite      = (t & 1) ? hb0 : hb1;

        // ---- WAIT half of the step barrier (epoch t) ----
        if (t > 0) {
            if (tid == 0) {
                while (__hip_atomic_load(gen, __ATOMIC_RELAXED,
                                         __HIP_MEMORY_SCOPE_AGENT) < (unsigned)t)
                    __builtin_amdgcn_s_sleep(1);
            }
            __syncthreads();
        }

        // ---- stage h panel: h[16x1024] MALL-direct ----
        int4v htmp[8];
        #pragma unroll
        for (int u = 0; u < 8; ++u) {
            const int idx = u * 256 + tid;          // 0..2047
            const int row = idx >> 7;               // 0..15
            const int col = (idx & 127) * 8;        // 0..1016
            const unsigned short* src = hread + (size_t)(b0 + row) * H_DIM + col;
            asm volatile("global_load_dwordx4 %0, %1, off sc0 sc1"
                         : "=v"(htmp[u]) : "v"(src) : "memory");
        }
        asm volatile("s_waitcnt vmcnt(0)" ::: "memory");
        #pragma unroll
        for (int u = 0; u < 8; ++u) {
            const int idx = u * 256 + tid;
            const int row = idx >> 7;
            const int col = (idx & 127) * 8;
            *(int4v*)(&Alds[row * A_STRIDE + col]) = htmp[u];
        }
        __syncthreads();

        // ---- h K-loop: 32 chunks x 2 gate-subtiles, starting from xacc ----
        f32x4 acc0 = xacc0;
        f32x4 acc1 = xacc1;
        #pragma unroll
        for (int c = 0; c < 32; ++c) {
            short8 a = *(const short8*)(&Alds[cl * A_STRIDE + c * 32 + quad * 8]);
            acc0 = __builtin_amdgcn_mfma_f32_16x16x32_bf16(a, Wreg[c],      acc0, 0, 0, 0);
            acc1 = __builtin_amdgcn_mfma_f32_16x16x32_bf16(a, Wreg[40 + c], acc1, 0, 0, 0);
        }

        // ---- pointwise: 4x4 xor-transpose within each gate-quad ----
        // lane q_g owns cell (b = quad*4+q_g, j = j0+wid*8+s*4+jl) with gates
        // in slots 0..3 -- 2 cells/lane instead of 8 redundant ones.
        float hn[2];
        #pragma unroll
        for (int s = 0; s < 2; ++s) {
            const f32x4 accv = s ? acc1 : acc0;
            const float bs   = s ? bias1 : bias0;
            float e[4];
            #pragma unroll
            for (int r = 0; r < 4; ++r) e[r] = accv[r] + bs;
            float t1[4];
            #pragma unroll
            for (int r = 0; r < 4; ++r) t1[r] = __shfl_xor(e[r ^ 1], 1);
            #pragma unroll
            for (int r = 0; r < 4; ++r) e[r] = ((q_g ^ r) & 1) ? t1[r] : e[r];
            float t2[4];
            #pragma unroll
            for (int r = 0; r < 4; ++r) t2[r] = __shfl_xor(e[r ^ 2], 2);
            #pragma unroll
            for (int r = 0; r < 4; ++r) e[r] = ((q_g ^ r) & 2) ? t2[r] : e[r];

            const float ig = sigmoid_f(e[0]);
            const float fg = sigmoid_f(e[1]);
            const float gg = tanh_f(e[2]);
            const float og = sigmoid_f(e[3]);
            const float cp = s ? c1v : c0v;
            const float cn = fg * cp + ig * gg;
            if (s) c1v = cn; else c0v = cn;
            hn[s] = og * tanh_f(cn);
        }

        // ---- pack 8 cols (both subtiles) -> one 16B store per cell-row ----
        const unsigned short hb16_0 = f2bf(hn[0]);
        const unsigned short hb16_1 = f2bf(hn[1]);
        unsigned p32_0 = (unsigned)hb16_0 |
            ((unsigned)(unsigned short)__shfl_xor((int)hb16_0, 4) << 16);
        unsigned p32_1 = (unsigned)hb16_1 |
            ((unsigned)(unsigned short)__shfl_xor((int)hb16_1, 4) << 16);
        unsigned hi_0 = (unsigned)__shfl_xor((int)p32_0, 8);
        unsigned hi_1 = (unsigned)__shfl_xor((int)p32_1, 8);

        const int brow = quad * 4 + q_g;
        if (jl == 0 && t + 1 < T_DIM) {    // 16 lanes/wave: (quad, q_g)
            int4v val;
            val.x = (int)p32_0; val.y = (int)hi_0;
            val.z = (int)p32_1; val.w = (int)hi_1;
            unsigned short* dst =
                hwrite + (size_t)(b0 + brow) * H_DIM + j0 + wid * 8;
            asm volatile("global_store_dwordx4 %0, %1, off sc0 sc1"
                         :: "v"(dst), "v"(val) : "memory");
        }
        if (t == T_DIM - 1) {
            const size_t base = (size_t)(b0 + brow) * H_DIM + j0 + wid * 8 + jl;
            hf32[base]     = hn[0];
            hf32[base + 4] = hn[1];
            // hf32 stores drain at kernel end (dispatch boundary)
        }

        // ---- ARRIVE half of the step barrier (epoch t+1) + x overlap ----
        if (t + 1 < T_DIM) {
            __syncthreads();   // vmcnt drain: h stores acked at the MALL
            if (tid == 0) {
                unsigned old = __hip_atomic_fetch_add(cnt, 1u, __ATOMIC_RELAXED,
                                                      __HIP_MEMORY_SCOPE_AGENT);
                if (old == 31u) {   // last arriver: reset + release generation
                    __hip_atomic_store(cnt, 0u, __ATOMIC_RELAXED,
                                       __HIP_MEMORY_SCOPE_AGENT);
                    __hip_atomic_store(gen, (unsigned)(t + 1), __ATOMIC_RELEASE,
                                       __HIP_MEMORY_SCOPE_AGENT);
                }
            }
            // overlap window: stage x_{t+1} and compute its gate contribution
            #pragma unroll
            for (int u = 0; u < 2; ++u) {
                const int idx = u * 256 + tid;      // 0..511
                const int row = idx >> 5;           // 0..15
                const int col = (idx & 31) * 8;     // 0..248
                short8 xv = *(const short8*)(xbf + (size_t)(b0 + row) * (T_DIM * I_DIMV)
                                             + (size_t)(t + 1) * I_DIMV + col);
                *(short8*)(&Alds[row * A_STRIDE + 1024 + col]) = xv;
            }
            __syncthreads();   // x_{t+1} staged (h region untouched)
            xacc0 = (f32x4){0.f, 0.f, 0.f, 0.f};
            xacc1 = (f32x4){0.f, 0.f, 0.f, 0.f};
            #pragma unroll
            for (int c = 0; c < 8; ++c) {
                short8 a = *(const short8*)(&Alds[cl * A_STRIDE + 1024 + c * 32 + quad * 8]);
                xacc0 = __builtin_amdgcn_mfma_f32_16x16x32_bf16(a, Wreg[32 + c], xacc0, 0, 0, 0);
                xacc1 = __builtin_amdgcn_mfma_f32_16x16x32_bf16(a, Wreg[72 + c], xacc1, 0, 0, 0);
            }
        }
    }
}

// ---------------------------------------------------------------------------
// Final fc: out[128,1000] = h @ fc_W^T + fc_b, fp32. Overwrites the bar
// region of d_out with real results (runs strictly after lstm_grid).
// ---------------------------------------------------------------------------
__global__ __launch_bounds__(256)
void fc_kernel(const float* __restrict__ hf32,
               const float* __restrict__ fcW,
               const float* __restrict__ fcb,
               float* __restrict__ out)
{
    __shared__ __align__(16) float hs[16 * 256];
    const int tid = threadIdx.x;
    const int b0 = blockIdx.x * 16;
    const int o0 = blockIdx.y * 64;
    const int to = tid & 63;
    const int tb = tid >> 6;
    const int o  = o0 + to;
    const bool active = (o < C_DIM);

    float acc[4] = {0.f, 0.f, 0.f, 0.f};

    for (int jc = 0; jc < H_DIM; jc += 256) {
        __syncthreads();
        {
            const int row = tid >> 4;
            const int c0  = (tid & 15) * 16;
            #pragma unroll
            for (int u = 0; u < 4; ++u) {
                *(f32x4*)(&hs[row * 256 + c0 + u * 4]) =
                    *(const f32x4*)(hf32 + (size_t)(b0 + row) * H_DIM + jc + c0 + u * 4);
            }
        }
        __syncthreads();
        if (active) {
            for (int j4 = 0; j4 < 256; j4 += 4) {
                f32x4 wv = *(const f32x4*)(fcW + (size_t)o * H_DIM + jc + j4);
                #pragma unroll
                for (int bb = 0; bb < 4; ++bb) {
                    f32x4 hv = *(const f32x4*)(&hs[(tb * 4 + bb) * 256 + j4]);
                    acc[bb] += wv.x * hv.x + wv.y * hv.y + wv.z * hv.z + wv.w * hv.w;
                }
            }
        }
    }
    if (active) {
        const float bias = fcb[o];
        #pragma unroll
        for (int bb = 0; bb < 4; ++bb) {
            out[(size_t)(b0 + tb * 4 + bb) * C_DIM + o] = acc[bb] + bias;
        }
    }
}

extern "C" void kernel_launch(void* const* d_in, const int* in_sizes, int n_in,
                              void* d_out, int out_size, void* d_ws, size_t ws_size,
                              hipStream_t stream)
{
    const float* x   = (const float*)d_in[0];
    const float* Wih = (const float*)d_in[1];
    const float* Whh = (const float*)d_in[2];
    const float* bih = (const float*)d_in[3];
    const float* bhh = (const float*)d_in[4];
    const float* fcW = (const float*)d_in[5];
    const float* fcb = (const float*)d_in[6];
    float* out = (float*)d_out;

    char* ws = (char*)d_ws;
    unsigned short* Wc  = (unsigned short*)(ws + 0);         // 10,485,760 B
    unsigned short* xbf = (unsigned short*)(ws + 10485760);  // 33,554,432 B
    float* biasc        = (float*)(ws + 44040192);           //     16,384 B
    unsigned short* hb0 = (unsigned short*)(ws + 44056576);  //    262,144 B
    unsigned short* hb1 = (unsigned short*)(ws + 44318720);  //    262,144 B
    float* hf32         = (float*)(ws + 44580864);           //    524,288 B
    // total ws use: 45,105,152 B (identical to the proven layout)
    unsigned* bar       = (unsigned*)d_out;  // 4 KB of d_out (512,000 B);
                                             // fc_kernel overwrites it last.

    hipLaunchKernelGGL(prep_kernel, dim3(1024), dim3(256), 0, stream,
                       x, Wih, Whh, bih, bhh, Wc, xbf, biasc, hb0, bar);

    hipLaunchKernelGGL(lstm_grid, dim3(256), dim3(256), 0, stream,
                       Wc, xbf, biasc, hb0, hb1, hf32, bar);

    hipLaunchKernelGGL(fc_kernel, dim3(8, 16), dim3(256), 0, stream,
                       hf32, fcW, fcb, out);
}

// Round 7
// 2006.226 us; speedup vs baseline: 1.2358x; 1.2358x over previous
//
#include <hip/hip_runtime.h>
#include <hip/hip_bf16.h>

#define B_DIM 128
#define T_DIM 512
#define I_DIMV 256
#define H_DIM 1024
#define G_DIM 4096
#define K_TOT 1280
#define C_DIM 1000
#define A_STRIDE 1288   // 1280 + 8 shorts pad (byte stride 2576, 16B aligned)

typedef __attribute__((ext_vector_type(8))) short short8;
typedef __attribute__((ext_vector_type(4))) float f32x4;
typedef __attribute__((ext_vector_type(4))) unsigned short ushort4v;
typedef __attribute__((ext_vector_type(4))) int int4v;

__device__ __forceinline__ unsigned short f2bf(float f) {
    unsigned int u = __float_as_uint(f);
    u += 0x7FFF + ((u >> 16) & 1);   // round-to-nearest-even
    return (unsigned short)(u >> 16);
}

__device__ __forceinline__ float sigmoid_f(float x) {
    return __builtin_amdgcn_rcpf(1.0f + __expf(-x));
}
__device__ __forceinline__ float tanh_f(float x) {
    return 1.0f - 2.0f * __builtin_amdgcn_rcpf(1.0f + __expf(2.0f * x));
}

// ---------------------------------------------------------------------------
// Prologue: combined bf16 weights (gate-interleaved rows p = j*4+q), bf16 x,
// combined bias, zeroed h0, zeroed flag state (in d_out). Runs every call.
// ---------------------------------------------------------------------------
__global__ void prep_kernel(const float* __restrict__ x,
                            const float* __restrict__ Wih,
                            const float* __restrict__ Whh,
                            const float* __restrict__ bih,
                            const float* __restrict__ bhh,
                            unsigned short* __restrict__ Wc,
                            unsigned short* __restrict__ xbf,
                            float* __restrict__ biasc,
                            unsigned short* __restrict__ h0,
                            unsigned* __restrict__ bar)
{
    const int tid = blockIdx.x * blockDim.x + threadIdx.x;
    const int nth = gridDim.x * blockDim.x;

    const int WcN4 = G_DIM * K_TOT / 4;
    for (int i = tid; i < WcN4; i += nth) {
        int p = i / (K_TOT / 4);
        int k = (i - p * (K_TOT / 4)) * 4;
        int j = p >> 2, q = p & 3;
        int r = q * H_DIM + j;
        const float* src = (k < H_DIM) ? (Whh + (size_t)r * H_DIM + k)
                                       : (Wih + (size_t)r * I_DIMV + (k - H_DIM));
        f32x4 v = *(const f32x4*)src;
        ushort4v o;
        o.x = f2bf(v.x); o.y = f2bf(v.y); o.z = f2bf(v.z); o.w = f2bf(v.w);
        *(ushort4v*)(Wc + (size_t)i * 4) = o;
    }
    const int xN4 = B_DIM * T_DIM * I_DIMV / 4;
    for (int i = tid; i < xN4; i += nth) {
        f32x4 v = *(const f32x4*)(x + (size_t)i * 4);
        ushort4v o;
        o.x = f2bf(v.x); o.y = f2bf(v.y); o.z = f2bf(v.z); o.w = f2bf(v.w);
        *(ushort4v*)(xbf + (size_t)i * 4) = o;
    }
    for (int p = tid; p < G_DIM; p += nth) {
        int j = p >> 2, q = p & 3;
        int r = q * H_DIM + j;
        biasc[p] = bih[r] + bhh[r];
    }
    const int hN4 = B_DIM * H_DIM / 4;
    for (int i = tid; i < hN4; i += nth) {
        ushort4v z = {0, 0, 0, 0};
        *(ushort4v*)(h0 + (size_t)i * 4) = z;
    }
    // flags: 8 groups x 32 producers, CONTIGUOUS u32 per group -> one 128B
    // line per group at bar + 256*g. (R2's mistake was 128B stride per flag.)
    for (int i = tid; i < 2048; i += nth) bar[i] = 0;
}

// ---------------------------------------------------------------------------
// Persistent LSTM, plain launch. 256 WGs x 256 threads; co-residency is
// structural (LDS 41KB, 1 WG/CU by VGPR budget; 256 WGs on 256 CUs -> all
// dispatched immediately).
// WG: m_blk = wgid>>5 -> batches [16*m_blk, +16) (= sync group)
//     n_blk = wgid&31 -> hidden [32*n_blk, +32) == gate rows [128*n_blk,+128)
// W slice in registers for all 512 steps. h exchanged MALL-direct (sc0 sc1).
// Sync (NEW): one-sided per-producer flags, 32 contiguous u32 in ONE 128B
// MALL line per group. Producer: __syncthreads (vmcnt drain -> h stores
// acked at MALL) then tid0 stores flag[n]=t+1 sc0sc1. Consumer: ALL waves
// poll the line wave-parallel (one transaction), ballot, then issue h loads.
// Removes the rendezvous fetch_add + gen-release hops (2 RTs -> 1).
// Skew safety: flag[q] >= t  =>  q finished step t-1  =>  q done READING
// h_{t-1}; a WG only writes h_{t+1} (into h_{t-1}'s buffer) after observing
// all flags >= t, so the 2-buffer ping-pong invariant holds (max skew 1).
// Ordering: consumer h-loads are issued only after its flag-load (serviced
// at the MALL) showed t; producer h-stores were acked at the MALL before its
// flag store issued => later-serviced consumer loads see h_t. All cross-XCD
// traffic is sc0 sc1 (MALL-direct; R4/R5's sc0-only flags could deadlock).
// h load is column-split into two halves; K chunks 0..15 run while the
// second half's loads land (vmcnt(4) / vmcnt(0) pipelining).
// ---------------------------------------------------------------------------
__global__ __launch_bounds__(256, 1)
void lstm_grid(const unsigned short* __restrict__ Wc,
               const unsigned short* __restrict__ xbf,
               const float* __restrict__ biasc,
               unsigned short* __restrict__ hb0,
               unsigned short* __restrict__ hb1,
               float* __restrict__ hf32,
               unsigned* __restrict__ bar)
{
    __shared__ __align__(16) unsigned short Alds[16 * A_STRIDE];  // 41,216 B

    const int tid   = threadIdx.x;
    const int wgid  = blockIdx.x;
    const int m_blk = wgid >> 5;
    const int n_blk = wgid & 31;
    const int b0 = m_blk * 16;         // batch rows [b0, b0+16)
    const int p0 = n_blk * 128;        // gate rows  [p0, p0+128)
    const int j0 = n_blk * 32;         // hidden cols [j0, j0+32)

    const int wid  = tid >> 6;         // wave -> gate cols [wid*32, +32)
    const int lane = tid & 63;
    const int cl   = lane & 15;
    const int quad = lane >> 4;
    const int q_g  = cl & 3;           // gate: 0=i 1=f 2=g 3=o
    const int jl   = cl >> 2;

    const float bias0 = biasc[p0 + wid * 32 + cl];
    const float bias1 = biasc[p0 + wid * 32 + 16 + cl];

    // W slice in registers: 2 subtiles x 40 k-chunks = 80 x short8 (320 regs)
    // chunks 0..31 = h part (k 0..1023), chunks 32..39 = x part (k 1024..1279)
    short8 Wreg[80];
    {
        const unsigned short* w0 = Wc + (size_t)(p0 + wid * 32 + cl) * K_TOT + quad * 8;
        const unsigned short* w1 = w0 + (size_t)16 * K_TOT;
        #pragma unroll
        for (int c = 0; c < 40; ++c) {
            Wreg[c]      = *(const short8*)(w0 + c * 32);
            Wreg[40 + c] = *(const short8*)(w1 + c * 32);
        }
    }

    // flags: one 128B line per group (in d_out; fc_kernel overwrites later)
    unsigned* const flags    = bar + 256 * m_blk;
    unsigned* const own_flag = flags + n_blk;

    float c0v = 0.0f, c1v = 0.0f;      // cell state: 1 cell/lane per subtile

    // ---- prologue: stage x_0, compute xacc_0 ----
    f32x4 xacc0 = {0.f, 0.f, 0.f, 0.f};
    f32x4 xacc1 = {0.f, 0.f, 0.f, 0.f};
    {
        #pragma unroll
        for (int u = 0; u < 2; ++u) {
            const int idx = u * 256 + tid;          // 0..511
            const int row = idx >> 5;               // 0..15
            const int col = (idx & 31) * 8;         // 0..248
            short8 xv = *(const short8*)(xbf + (size_t)(b0 + row) * (T_DIM * I_DIMV)
                                         + col);
            *(short8*)(&Alds[row * A_STRIDE + 1024 + col]) = xv;
        }
        __syncthreads();
        #pragma unroll
        for (int c = 0; c < 8; ++c) {
            short8 a = *(const short8*)(&Alds[cl * A_STRIDE + 1024 + c * 32 + quad * 8]);
            xacc0 = __builtin_amdgcn_mfma_f32_16x16x32_bf16(a, Wreg[32 + c], xacc0, 0, 0, 0);
            xacc1 = __builtin_amdgcn_mfma_f32_16x16x32_bf16(a, Wreg[72 + c], xacc1, 0, 0, 0);
        }
    }

    const int colh = lane * 8;         // h-load: col offset in shorts (0..504)

    for (int t = 0; t < T_DIM; ++t) {
        const unsigned short* hread = (t & 1) ? hb1 : hb0;
        unsigned short* hwrite      = (t & 1) ? hb0 : hb1;

        // ---- wait for h_t: all waves poll the single flag line ----
        if (t > 0) {
            while (true) {
                unsigned v = 0xFFFFFFFFu;
                if (lane < 32) {
                    const unsigned* p = flags + lane;
                    asm volatile("global_load_dword %0, %1, off sc0 sc1"
                                 : "=v"(v) : "v"(p) : "memory");
                    asm volatile("s_waitcnt vmcnt(0)" ::: "memory");
                }
                if (__ballot(v >= (unsigned)t) == ~0ull) break;
                __builtin_amdgcn_s_sleep(1);
            }
        }

        // ---- h panel loads, column-split halves (each: 16 rows x 512 cols)
        // per thread: row = u*4 + wid, col = lane*8 (+512 for half B)
        int4v htA[4], htB[4];
        #pragma unroll
        for (int u = 0; u < 4; ++u) {
            const int row = u * 4 + wid;
            const unsigned short* src = hread + (size_t)(b0 + row) * H_DIM + colh;
            asm volatile("global_load_dwordx4 %0, %1, off sc0 sc1"
                         : "=v"(htA[u]) : "v"(src) : "memory");
        }
        #pragma unroll
        for (int u = 0; u < 4; ++u) {
            const int row = u * 4 + wid;
            const unsigned short* src = hread + (size_t)(b0 + row) * H_DIM + 512 + colh;
            asm volatile("global_load_dwordx4 %0, %1, off sc0 sc1"
                         : "=v"(htB[u]) : "v"(src) : "memory");
        }
        asm volatile("s_waitcnt vmcnt(4)" ::: "memory");   // half A landed
        #pragma unroll
        for (int u = 0; u < 4; ++u) {
            *(int4v*)(&Alds[(u * 4 + wid) * A_STRIDE + colh]) = htA[u];
        }
        __syncthreads();

        // ---- K chunks 0..15 (cols 0..511) while half B lands ----
        f32x4 acc0 = xacc0;
        f32x4 acc1 = xacc1;
        #pragma unroll
        for (int c = 0; c < 16; ++c) {
            short8 a = *(const short8*)(&Alds[cl * A_STRIDE + c * 32 + quad * 8]);
            acc0 = __builtin_amdgcn_mfma_f32_16x16x32_bf16(a, Wreg[c],      acc0, 0, 0, 0);
            acc1 = __builtin_amdgcn_mfma_f32_16x16x32_bf16(a, Wreg[40 + c], acc1, 0, 0, 0);
        }

        asm volatile("s_waitcnt vmcnt(0)" ::: "memory");   // half B landed
        #pragma unroll
        for (int u = 0; u < 4; ++u) {
            *(int4v*)(&Alds[(u * 4 + wid) * A_STRIDE + 512 + colh]) = htB[u];
        }
        __syncthreads();

        // ---- K chunks 16..31 (cols 512..1023) ----
        #pragma unroll
        for (int c = 16; c < 32; ++c) {
            short8 a = *(const short8*)(&Alds[cl * A_STRIDE + c * 32 + quad * 8]);
            acc0 = __builtin_amdgcn_mfma_f32_16x16x32_bf16(a, Wreg[c],      acc0, 0, 0, 0);
            acc1 = __builtin_amdgcn_mfma_f32_16x16x32_bf16(a, Wreg[40 + c], acc1, 0, 0, 0);
        }

        // ---- pointwise: 4x4 xor-transpose within each gate-quad ----
        // lane q_g owns cell (b = quad*4+q_g, j = j0+wid*8+s*4+jl) with gates
        // in slots 0..3 -- 2 cells/lane instead of 8 redundant ones.
        float hn[2];
        #pragma unroll
        for (int s = 0; s < 2; ++s) {
            const f32x4 accv = s ? acc1 : acc0;
            const float bs   = s ? bias1 : bias0;
            float e[4];
            #pragma unroll
            for (int r = 0; r < 4; ++r) e[r] = accv[r] + bs;
            float t1[4];
            #pragma unroll
            for (int r = 0; r < 4; ++r) t1[r] = __shfl_xor(e[r ^ 1], 1);
            #pragma unroll
            for (int r = 0; r < 4; ++r) e[r] = ((q_g ^ r) & 1) ? t1[r] : e[r];
            float t2[4];
            #pragma unroll
            for (int r = 0; r < 4; ++r) t2[r] = __shfl_xor(e[r ^ 2], 2);
            #pragma unroll
            for (int r = 0; r < 4; ++r) e[r] = ((q_g ^ r) & 2) ? t2[r] : e[r];

            const float ig = sigmoid_f(e[0]);
            const float fg = sigmoid_f(e[1]);
            const float gg = tanh_f(e[2]);
            const float og = sigmoid_f(e[3]);
            const float cp = s ? c1v : c0v;
            const float cn = fg * cp + ig * gg;
            if (s) c1v = cn; else c0v = cn;
            hn[s] = og * tanh_f(cn);
        }

        // ---- pack 8 cols (both subtiles) -> one 16B store per cell-row ----
        const unsigned short hb16_0 = f2bf(hn[0]);
        const unsigned short hb16_1 = f2bf(hn[1]);
        unsigned p32_0 = (unsigned)hb16_0 |
            ((unsigned)(unsigned short)__shfl_xor((int)hb16_0, 4) << 16);
        unsigned p32_1 = (unsigned)hb16_1 |
            ((unsigned)(unsigned short)__shfl_xor((int)hb16_1, 4) << 16);
        unsigned hi_0 = (unsigned)__shfl_xor((int)p32_0, 8);
        unsigned hi_1 = (unsigned)__shfl_xor((int)p32_1, 8);

        const int brow = quad * 4 + q_g;
        if (jl == 0 && t + 1 < T_DIM) {    // 16 lanes/wave: (quad, q_g)
            int4v val;
            val.x = (int)p32_0; val.y = (int)hi_0;
            val.z = (int)p32_1; val.w = (int)hi_1;
            unsigned short* dst =
                hwrite + (size_t)(b0 + brow) * H_DIM + j0 + wid * 8;
            asm volatile("global_store_dwordx4 %0, %1, off sc0 sc1"
                         :: "v"(dst), "v"(val) : "memory");
        }
        if (t == T_DIM - 1) {
            const size_t base = (size_t)(b0 + brow) * H_DIM + j0 + wid * 8 + jl;
            hf32[base]     = hn[0];
            hf32[base + 4] = hn[1];
            // hf32 stores drain at kernel end (dispatch boundary)
        }

        // ---- publish h_{t+1}, then x_{t+1} overlap work ----
        if (t + 1 < T_DIM) {
            __syncthreads();   // vmcnt drain: all waves' h stores acked at MALL
            if (tid == 0) {
                unsigned e = (unsigned)(t + 1);
                asm volatile("global_store_dword %0, %1, off sc0 sc1"
                             :: "v"(own_flag), "v"(e) : "memory");
            }
            // overlap window: stage x_{t+1} and compute its gate contribution
            #pragma unroll
            for (int u = 0; u < 2; ++u) {
                const int idx = u * 256 + tid;      // 0..511
                const int row = idx >> 5;           // 0..15
                const int col = (idx & 31) * 8;     // 0..248
                short8 xv = *(const short8*)(xbf + (size_t)(b0 + row) * (T_DIM * I_DIMV)
                                             + (size_t)(t + 1) * I_DIMV + col);
                *(short8*)(&Alds[row * A_STRIDE + 1024 + col]) = xv;
            }
            __syncthreads();   // x_{t+1} staged (h region untouched)
            xacc0 = (f32x4){0.f, 0.f, 0.f, 0.f};
            xacc1 = (f32x4){0.f, 0.f, 0.f, 0.f};
            #pragma unroll
            for (int c = 0; c < 8; ++c) {
                short8 a = *(const short8*)(&Alds[cl * A_STRIDE + 1024 + c * 32 + quad * 8]);
                xacc0 = __builtin_amdgcn_mfma_f32_16x16x32_bf16(a, Wreg[32 + c], xacc0, 0, 0, 0);
                xacc1 = __builtin_amdgcn_mfma_f32_16x16x32_bf16(a, Wreg[72 + c], xacc1, 0, 0, 0);
            }
        }
    }
}

// ---------------------------------------------------------------------------
// Final fc: out[128,1000] = h @ fc_W^T + fc_b, fp32. Overwrites the flag
// region of d_out with real results (runs strictly after lstm_grid).
// ---------------------------------------------------------------------------
__global__ __launch_bounds__(256)
void fc_kernel(const float* __restrict__ hf32,
               const float* __restrict__ fcW,
               const float* __restrict__ fcb,
               float* __restrict__ out)
{
    __shared__ __align__(16) float hs[16 * 256];
    const int tid = threadIdx.x;
    const int b0 = blockIdx.x * 16;
    const int o0 = blockIdx.y * 64;
    const int to = tid & 63;
    const int tb = tid >> 6;
    const int o  = o0 + to;
    const bool active = (o < C_DIM);

    float acc[4] = {0.f, 0.f, 0.f, 0.f};

    for (int jc = 0; jc < H_DIM; jc += 256) {
        __syncthreads();
        {
            const int row = tid >> 4;
            const int c0  = (tid & 15) * 16;
            #pragma unroll
            for (int u = 0; u < 4; ++u) {
                *(f32x4*)(&hs[row * 256 + c0 + u * 4]) =
                    *(const f32x4*)(hf32 + (size_t)(b0 + row) * H_DIM + jc + c0 + u * 4);
            }
        }
        __syncthreads();
        if (active) {
            for (int j4 = 0; j4 < 256; j4 += 4) {
                f32x4 wv = *(const f32x4*)(fcW + (size_t)o * H_DIM + jc + j4);
                #pragma unroll
                for (int bb = 0; bb < 4; ++bb) {
                    f32x4 hv = *(const f32x4*)(&hs[(tb * 4 + bb) * 256 + j4]);
                    acc[bb] += wv.x * hv.x + wv.y * hv.y + wv.z * hv.z + wv.w * hv.w;
                }
            }
        }
    }
    if (active) {
        const float bias = fcb[o];
        #pragma unroll
        for (int bb = 0; bb < 4; ++bb) {
            out[(size_t)(b0 + tb * 4 + bb) * C_DIM + o] = acc[bb] + bias;
        }
    }
}

extern "C" void kernel_launch(void* const* d_in, const int* in_sizes, int n_in,
                              void* d_out, int out_size, void* d_ws, size_t ws_size,
                              hipStream_t stream)
{
    const float* x   = (const float*)d_in[0];
    const float* Wih = (const float*)d_in[1];
    const float* Whh = (const float*)d_in[2];
    const float* bih = (const float*)d_in[3];
    const float* bhh = (const float*)d_in[4];
    const float* fcW = (const float*)d_in[5];
    const float* fcb = (const float*)d_in[6];
    float* out = (float*)d_out;

    char* ws = (char*)d_ws;
    unsigned short* Wc  = (unsigned short*)(ws + 0);         // 10,485,760 B
    unsigned short* xbf = (unsigned short*)(ws + 10485760);  // 33,554,432 B
    float* biasc        = (float*)(ws + 44040192);           //     16,384 B
    unsigned short* hb0 = (unsigned short*)(ws + 44056576);  //    262,144 B
    unsigned short* hb1 = (unsigned short*)(ws + 44318720);  //    262,144 B
    float* hf32         = (float*)(ws + 44580864);           //    524,288 B
    // total ws use: 45,105,152 B (identical to the proven layout)
    unsigned* bar       = (unsigned*)d_out;  // 8 KB of d_out (512,000 B);
                                             // fc_kernel overwrites it last.

    hipLaunchKernelGGL(prep_kernel, dim3(1024), dim3(256), 0, stream,
                       x, Wih, Whh, bih, bhh, Wc, xbf, biasc, hb0, bar);

    hipLaunchKernelGGL(lstm_grid, dim3(256), dim3(256), 0, stream,
                       Wc, xbf, biasc, hb0, hb1, hf32, bar);

    hipLaunchKernelGGL(fc_kernel, dim3(8, 16), dim3(256), 0, stream,
                       hf32, fcW, fcb, out);
}

// Round 8
// 1720.966 us; speedup vs baseline: 1.4407x; 1.1658x over previous
//
#include <hip/hip_runtime.h>
#include <hip/hip_bf16.h>

#define B_DIM 128
#define T_DIM 512
#define I_DIMV 256
#define H_DIM 1024
#define G_DIM 4096
#define K_TOT 1280
#define C_DIM 1000
#define A_STRIDE 1288   // 1280 + 8 shorts pad (byte stride 2576, 16B aligned)

typedef __attribute__((ext_vector_type(8))) short short8;
typedef __attribute__((ext_vector_type(4))) float f32x4;
typedef __attribute__((ext_vector_type(4))) unsigned short ushort4v;
typedef __attribute__((ext_vector_type(4))) int int4v;

__device__ __forceinline__ unsigned short f2bf(float f) {
    unsigned int u = __float_as_uint(f);
    u += 0x7FFF + ((u >> 16) & 1);   // round-to-nearest-even
    return (unsigned short)(u >> 16);
}

__device__ __forceinline__ float sigmoid_f(float x) {
    return __builtin_amdgcn_rcpf(1.0f + __expf(-x));
}
__device__ __forceinline__ float tanh_f(float x) {
    return 1.0f - 2.0f * __builtin_amdgcn_rcpf(1.0f + __expf(2.0f * x));
}

// ---------------------------------------------------------------------------
// Prologue: combined bf16 weights (gate-interleaved rows p = j*4+q), bf16 x,
// combined bias, zeroed h0, zeroed sync/probe state (in d_out).
// ---------------------------------------------------------------------------
__global__ void prep_kernel(const float* __restrict__ x,
                            const float* __restrict__ Wih,
                            const float* __restrict__ Whh,
                            const float* __restrict__ bih,
                            const float* __restrict__ bhh,
                            unsigned short* __restrict__ Wc,
                            unsigned short* __restrict__ xbf,
                            float* __restrict__ biasc,
                            unsigned short* __restrict__ h0,
                            unsigned* __restrict__ bar)
{
    const int tid = blockIdx.x * blockDim.x + threadIdx.x;
    const int nth = gridDim.x * blockDim.x;

    const int WcN4 = G_DIM * K_TOT / 4;
    for (int i = tid; i < WcN4; i += nth) {
        int p = i / (K_TOT / 4);
        int k = (i - p * (K_TOT / 4)) * 4;
        int j = p >> 2, q = p & 3;
        int r = q * H_DIM + j;
        const float* src = (k < H_DIM) ? (Whh + (size_t)r * H_DIM + k)
                                       : (Wih + (size_t)r * I_DIMV + (k - H_DIM));
        f32x4 v = *(const f32x4*)src;
        ushort4v o;
        o.x = f2bf(v.x); o.y = f2bf(v.y); o.z = f2bf(v.z); o.w = f2bf(v.w);
        *(ushort4v*)(Wc + (size_t)i * 4) = o;
    }
    const int xN4 = B_DIM * T_DIM * I_DIMV / 4;
    for (int i = tid; i < xN4; i += nth) {
        f32x4 v = *(const f32x4*)(x + (size_t)i * 4);
        ushort4v o;
        o.x = f2bf(v.x); o.y = f2bf(v.y); o.z = f2bf(v.z); o.w = f2bf(v.w);
        *(ushort4v*)(xbf + (size_t)i * 4) = o;
    }
    for (int p = tid; p < G_DIM; p += nth) {
        int j = p >> 2, q = p & 3;
        int r = q * H_DIM + j;
        biasc[p] = bih[r] + bhh[r];
    }
    const int hN4 = B_DIM * H_DIM / 4;
    for (int i = tid; i < hN4; i += nth) {
        ushort4v z = {0, 0, 0, 0};
        *(ushort4v*)(h0 + (size_t)i * 4) = z;
    }
    // bar layout (u32): [256*g .. +32)        step flags (one 128B line/grp)
    //                   [2048+256*g .. +32)   probe ready flags (MALL line)
    //                   [2048+256*g+32 ..+64) probe magic slots (separate line)
    for (int i = tid; i < 4096; i += nth) bar[i] = 0;
}

// ---------------------------------------------------------------------------
// Persistent LSTM. 256 WGs x 256 threads, 1 WG/CU -> all co-resident.
// Mapping: m_blk = wgid & 7 (sync group; XCD-local if dispatch round-robins),
//          n_blk = wgid >> 3.
// Sync: R7-proven one-sided flags (32 contiguous u32, one 128B line/group).
// NEW: functional XCD-coherence probe decides, per group, whether h + flags
// can use sc0-only (XCD L2, ~200cy) instead of sc0sc1 (MALL, ~900cy):
//   each WG sc0-stores a distinct magic; drains; publishes readiness on the
//   MALL flag line (proven poll); then sc0-reads all 32 magics. A reader
//   sees member j's magic IFF j's dirty line is in the reader's own L2
//   (same XCD) -- MALL holds prep's zero otherwise. Verdict is unanimous
//   within a group by symmetry, so no mixed-path group exists. l2path spins
//   only on flags proven L2-visible (R4/R5's cross-XCD sc0 deadlock is
//   structurally excluded); fallback is byte-identical R7 (MALL everywhere).
// Ordering (both paths): __syncthreads' vmcnt drain acks h stores at the
// coherence point (L2 or MALL) BEFORE the flag store issues; consumer polls
// the same point, then loads h from it. Skew <= 1, 2 buffers suffice.
// h load column-split; K chunks 0..15 overlap half B's landing. x_{t+1}
// staged + its 16 MFMAs computed in the publish window (independent of h).
// ---------------------------------------------------------------------------
__global__ __launch_bounds__(256, 1)
void lstm_grid(const unsigned short* __restrict__ Wc,
               const unsigned short* __restrict__ xbf,
               const float* __restrict__ biasc,
               unsigned short* __restrict__ hb0,
               unsigned short* __restrict__ hb1,
               float* __restrict__ hf32,
               unsigned* __restrict__ bar)
{
    __shared__ __align__(16) unsigned short Alds[16 * A_STRIDE];  // 41,216 B

    const int tid   = threadIdx.x;
    const int wgid  = blockIdx.x;
    const int m_blk = wgid & 7;        // sync group (intended XCD)
    const int n_blk = wgid >> 3;       // 0..31 within group
    const int b0 = m_blk * 16;         // batch rows [b0, b0+16)
    const int p0 = n_blk * 128;        // gate rows  [p0, p0+128)
    const int j0 = n_blk * 32;         // hidden cols [j0, j0+32)

    const int wid  = tid >> 6;         // wave -> gate cols [wid*32, +32)
    const int lane = tid & 63;
    const int cl   = lane & 15;
    const int quad = lane >> 4;
    const int q_g  = cl & 3;           // gate: 0=i 1=f 2=g 3=o
    const int jl   = cl >> 2;

    const float bias0 = biasc[p0 + wid * 32 + cl];
    const float bias1 = biasc[p0 + wid * 32 + 16 + cl];

    // W slice in registers: 2 subtiles x 40 k-chunks = 80 x short8 (320 regs)
    // chunks 0..31 = h part (k 0..1023), chunks 32..39 = x part (k 1024..1279)
    short8 Wreg[80];
    {
        const unsigned short* w0 = Wc + (size_t)(p0 + wid * 32 + cl) * K_TOT + quad * 8;
        const unsigned short* w1 = w0 + (size_t)16 * K_TOT;
        #pragma unroll
        for (int c = 0; c < 40; ++c) {
            Wreg[c]      = *(const short8*)(w0 + c * 32);
            Wreg[40 + c] = *(const short8*)(w1 + c * 32);
        }
    }

    unsigned* const flags    = bar + 256 * m_blk;        // step flags (MALL/L2)
    unsigned* const own_flag = flags + n_blk;
    unsigned* const pready   = bar + 2048 + 256 * m_blk; // probe ready (MALL)
    unsigned* const pmagic   = pready + 32;              // next 128B line (L2)

    // ---- functional XCD-coherence probe (once) ----
    bool l2path;
    {
        const unsigned mymagic = 0x5EED0000u | (unsigned)wgid;
        if (tid == 0) {
            unsigned* p = pmagic + n_blk;
            asm volatile("global_store_dword %0, %1, off sc0"
                         :: "v"(p), "v"(mymagic) : "memory");
        }
        __syncthreads();   // drain: magic acked at this WG's L2
        if (tid == 0) {
            unsigned one = 1u;
            unsigned* p = pready + n_blk;
            asm volatile("global_store_dword %0, %1, off sc0 sc1"
                         :: "v"(p), "v"(one) : "memory");
        }
        while (true) {     // proven MALL poll pattern
            unsigned v = 1u;
            if (lane < 32) {
                const unsigned* p = pready + lane;
                asm volatile("global_load_dword %0, %1, off sc0 sc1"
                             : "=v"(v) : "v"(p) : "memory");
                asm volatile("s_waitcnt vmcnt(0)" ::: "memory");
            }
            if (__ballot(v >= 1u) == ~0ull) break;
            __builtin_amdgcn_s_sleep(1);
        }
        unsigned expect = 0x5EED0000u | (unsigned)((lane << 3) | m_blk);
        unsigned got = expect;
        if (lane < 32) {
            const unsigned* p = pmagic + lane;
            asm volatile("global_load_dword %0, %1, off sc0"
                         : "=v"(got) : "v"(p) : "memory");
            asm volatile("s_waitcnt vmcnt(0)" ::: "memory");
        }
        l2path = (__ballot(got == expect) == ~0ull);   // unanimous per group
    }

    float c0v = 0.0f, c1v = 0.0f;      // cell state: 1 cell/lane per subtile

    // ---- prologue: stage x_0, compute xacc_0 ----
    f32x4 xacc0 = {0.f, 0.f, 0.f, 0.f};
    f32x4 xacc1 = {0.f, 0.f, 0.f, 0.f};
    {
        #pragma unroll
        for (int u = 0; u < 2; ++u) {
            const int idx = u * 256 + tid;          // 0..511
            const int row = idx >> 5;               // 0..15
            const int col = (idx & 31) * 8;         // 0..248
            short8 xv = *(const short8*)(xbf + (size_t)(b0 + row) * (T_DIM * I_DIMV)
                                         + col);
            *(short8*)(&Alds[row * A_STRIDE + 1024 + col]) = xv;
        }
        __syncthreads();
        #pragma unroll
        for (int c = 0; c < 8; ++c) {
            short8 a = *(const short8*)(&Alds[cl * A_STRIDE + 1024 + c * 32 + quad * 8]);
            xacc0 = __builtin_amdgcn_mfma_f32_16x16x32_bf16(a, Wreg[32 + c], xacc0, 0, 0, 0);
            xacc1 = __builtin_amdgcn_mfma_f32_16x16x32_bf16(a, Wreg[72 + c], xacc1, 0, 0, 0);
        }
    }

    const int colh = lane * 8;         // h-load: col offset in shorts (0..504)

    for (int t = 0; t < T_DIM; ++t) {
        const unsigned short* hread = (t & 1) ? hb1 : hb0;
        unsigned short* hwrite      = (t & 1) ? hb0 : hb1;

        // ---- wait for h_t: all waves poll the single flag line ----
        if (t > 0) {
            if (l2path) {
                while (true) {
                    unsigned v = 0xFFFFFFFFu;
                    if (lane < 32) {
                        const unsigned* p = flags + lane;
                        asm volatile("global_load_dword %0, %1, off sc0"
                                     : "=v"(v) : "v"(p) : "memory");
                        asm volatile("s_waitcnt vmcnt(0)" ::: "memory");
                    }
                    if (__ballot(v >= (unsigned)t) == ~0ull) break;
                    __builtin_amdgcn_s_sleep(1);
                }
            } else {
                while (true) {
                    unsigned v = 0xFFFFFFFFu;
                    if (lane < 32) {
                        const unsigned* p = flags + lane;
                        asm volatile("global_load_dword %0, %1, off sc0 sc1"
                                     : "=v"(v) : "v"(p) : "memory");
                        asm volatile("s_waitcnt vmcnt(0)" ::: "memory");
                    }
                    if (__ballot(v >= (unsigned)t) == ~0ull) break;
                    __builtin_amdgcn_s_sleep(1);
                }
            }
        }

        // ---- h panel loads, column-split halves (16 rows x 512 cols each) ----
        int4v htA[4], htB[4];
        if (l2path) {
            #pragma unroll
            for (int u = 0; u < 4; ++u) {
                const unsigned short* src =
                    hread + (size_t)(b0 + u * 4 + wid) * H_DIM + colh;
                asm volatile("global_load_dwordx4 %0, %1, off sc0"
                             : "=v"(htA[u]) : "v"(src) : "memory");
            }
            #pragma unroll
            for (int u = 0; u < 4; ++u) {
                const unsigned short* src =
                    hread + (size_t)(b0 + u * 4 + wid) * H_DIM + 512 + colh;
                asm volatile("global_load_dwordx4 %0, %1, off sc0"
                             : "=v"(htB[u]) : "v"(src) : "memory");
            }
        } else {
            #pragma unroll
            for (int u = 0; u < 4; ++u) {
                const unsigned short* src =
                    hread + (size_t)(b0 + u * 4 + wid) * H_DIM + colh;
                asm volatile("global_load_dwordx4 %0, %1, off sc0 sc1"
                             : "=v"(htA[u]) : "v"(src) : "memory");
            }
            #pragma unroll
            for (int u = 0; u < 4; ++u) {
                const unsigned short* src =
                    hread + (size_t)(b0 + u * 4 + wid) * H_DIM + 512 + colh;
                asm volatile("global_load_dwordx4 %0, %1, off sc0 sc1"
                             : "=v"(htB[u]) : "v"(src) : "memory");
            }
        }
        asm volatile("s_waitcnt vmcnt(4)" ::: "memory");   // half A landed
        #pragma unroll
        for (int u = 0; u < 4; ++u) {
            *(int4v*)(&Alds[(u * 4 + wid) * A_STRIDE + colh]) = htA[u];
        }
        __syncthreads();

        // ---- K chunks 0..15 (cols 0..511) while half B lands ----
        f32x4 acc0 = xacc0;
        f32x4 acc1 = xacc1;
        #pragma unroll
        for (int c = 0; c < 16; ++c) {
            short8 a = *(const short8*)(&Alds[cl * A_STRIDE + c * 32 + quad * 8]);
            acc0 = __builtin_amdgcn_mfma_f32_16x16x32_bf16(a, Wreg[c],      acc0, 0, 0, 0);
            acc1 = __builtin_amdgcn_mfma_f32_16x16x32_bf16(a, Wreg[40 + c], acc1, 0, 0, 0);
        }

        asm volatile("s_waitcnt vmcnt(0)" ::: "memory");   // half B landed
        #pragma unroll
        for (int u = 0; u < 4; ++u) {
            *(int4v*)(&Alds[(u * 4 + wid) * A_STRIDE + 512 + colh]) = htB[u];
        }
        __syncthreads();

        // ---- K chunks 16..31 (cols 512..1023) ----
        #pragma unroll
        for (int c = 16; c < 32; ++c) {
            short8 a = *(const short8*)(&Alds[cl * A_STRIDE + c * 32 + quad * 8]);
            acc0 = __builtin_amdgcn_mfma_f32_16x16x32_bf16(a, Wreg[c],      acc0, 0, 0, 0);
            acc1 = __builtin_amdgcn_mfma_f32_16x16x32_bf16(a, Wreg[40 + c], acc1, 0, 0, 0);
        }

        // ---- pointwise: 4x4 xor-transpose within each gate-quad ----
        float hn[2];
        #pragma unroll
        for (int s = 0; s < 2; ++s) {
            const f32x4 accv = s ? acc1 : acc0;
            const float bs   = s ? bias1 : bias0;
            float e[4];
            #pragma unroll
            for (int r = 0; r < 4; ++r) e[r] = accv[r] + bs;
            float t1[4];
            #pragma unroll
            for (int r = 0; r < 4; ++r) t1[r] = __shfl_xor(e[r ^ 1], 1);
            #pragma unroll
            for (int r = 0; r < 4; ++r) e[r] = ((q_g ^ r) & 1) ? t1[r] : e[r];
            float t2[4];
            #pragma unroll
            for (int r = 0; r < 4; ++r) t2[r] = __shfl_xor(e[r ^ 2], 2);
            #pragma unroll
            for (int r = 0; r < 4; ++r) e[r] = ((q_g ^ r) & 2) ? t2[r] : e[r];

            const float ig = sigmoid_f(e[0]);
            const float fg = sigmoid_f(e[1]);
            const float gg = tanh_f(e[2]);
            const float og = sigmoid_f(e[3]);
            const float cp = s ? c1v : c0v;
            const float cn = fg * cp + ig * gg;
            if (s) c1v = cn; else c0v = cn;
            hn[s] = og * tanh_f(cn);
        }

        // ---- pack 8 cols (both subtiles) -> one 16B store per cell-row ----
        const unsigned short hb16_0 = f2bf(hn[0]);
        const unsigned short hb16_1 = f2bf(hn[1]);
        unsigned p32_0 = (unsigned)hb16_0 |
            ((unsigned)(unsigned short)__shfl_xor((int)hb16_0, 4) << 16);
        unsigned p32_1 = (unsigned)hb16_1 |
            ((unsigned)(unsigned short)__shfl_xor((int)hb16_1, 4) << 16);
        unsigned hi_0 = (unsigned)__shfl_xor((int)p32_0, 8);
        unsigned hi_1 = (unsigned)__shfl_xor((int)p32_1, 8);

        const int brow = quad * 4 + q_g;
        if (jl == 0 && t + 1 < T_DIM) {    // 16 lanes/wave: (quad, q_g)
            int4v val;
            val.x = (int)p32_0; val.y = (int)hi_0;
            val.z = (int)p32_1; val.w = (int)hi_1;
            unsigned short* dst =
                hwrite + (size_t)(b0 + brow) * H_DIM + j0 + wid * 8;
            if (l2path) {
                asm volatile("global_store_dwordx4 %0, %1, off sc0"
                             :: "v"(dst), "v"(val) : "memory");
            } else {
                asm volatile("global_store_dwordx4 %0, %1, off sc0 sc1"
                             :: "v"(dst), "v"(val) : "memory");
            }
        }
        if (t == T_DIM - 1) {
            const size_t base = (size_t)(b0 + brow) * H_DIM + j0 + wid * 8 + jl;
            hf32[base]     = hn[0];
            hf32[base + 4] = hn[1];
            // hf32 stores drain at kernel end (dispatch boundary)
        }

        // ---- publish h_{t+1}, then x_{t+1} overlap work ----
        if (t + 1 < T_DIM) {
            __syncthreads();   // vmcnt drain: h stores acked at coherence point
            if (tid == 0) {
                unsigned e = (unsigned)(t + 1);
                if (l2path) {
                    asm volatile("global_store_dword %0, %1, off sc0"
                                 :: "v"(own_flag), "v"(e) : "memory");
                } else {
                    asm volatile("global_store_dword %0, %1, off sc0 sc1"
                                 :: "v"(own_flag), "v"(e) : "memory");
                }
            }
            // overlap window: stage x_{t+1} and compute its gate contribution
            #pragma unroll
            for (int u = 0; u < 2; ++u) {
                const int idx = u * 256 + tid;      // 0..511
                const int row = idx >> 5;           // 0..15
                const int col = (idx & 31) * 8;     // 0..248
                short8 xv = *(const short8*)(xbf + (size_t)(b0 + row) * (T_DIM * I_DIMV)
                                             + (size_t)(t + 1) * I_DIMV + col);
                *(short8*)(&Alds[row * A_STRIDE + 1024 + col]) = xv;
            }
            __syncthreads();   // x_{t+1} staged (h region untouched)
            xacc0 = (f32x4){0.f, 0.f, 0.f, 0.f};
            xacc1 = (f32x4){0.f, 0.f, 0.f, 0.f};
            #pragma unroll
            for (int c = 0; c < 8; ++c) {
                short8 a = *(const short8*)(&Alds[cl * A_STRIDE + 1024 + c * 32 + quad * 8]);
                xacc0 = __builtin_amdgcn_mfma_f32_16x16x32_bf16(a, Wreg[32 + c], xacc0, 0, 0, 0);
                xacc1 = __builtin_amdgcn_mfma_f32_16x16x32_bf16(a, Wreg[72 + c], xacc1, 0, 0, 0);
            }
        }
    }
}

// ---------------------------------------------------------------------------
// Final fc: out[128,1000] = h @ fc_W^T + fc_b, fp32. Overwrites the sync
// region of d_out with real results (runs strictly after lstm_grid).
// ---------------------------------------------------------------------------
__global__ __launch_bounds__(256)
void fc_kernel(const float* __restrict__ hf32,
               const float* __restrict__ fcW,
               const float* __restrict__ fcb,
               float* __restrict__ out)
{
    __shared__ __align__(16) float hs[16 * 256];
    const int tid = threadIdx.x;
    const int b0 = blockIdx.x * 16;
    const int o0 = blockIdx.y * 64;
    const int to = tid & 63;
    const int tb = tid >> 6;
    const int o  = o0 + to;
    const bool active = (o < C_DIM);

    float acc[4] = {0.f, 0.f, 0.f, 0.f};

    for (int jc = 0; jc < H_DIM; jc += 256) {
        __syncthreads();
        {
            const int row = tid >> 4;
            const int c0  = (tid & 15) * 16;
            #pragma unroll
            for (int u = 0; u < 4; ++u) {
                *(f32x4*)(&hs[row * 256 + c0 + u * 4]) =
                    *(const f32x4*)(hf32 + (size_t)(b0 + row) * H_DIM + jc + c0 + u * 4);
            }
        }
        __syncthreads();
        if (active) {
            for (int j4 = 0; j4 < 256; j4 += 4) {
                f32x4 wv = *(const f32x4*)(fcW + (size_t)o * H_DIM + jc + j4);
                #pragma unroll
                for (int bb = 0; bb < 4; ++bb) {
                    f32x4 hv = *(const f32x4*)(&hs[(tb * 4 + bb) * 256 + j4]);
                    acc[bb] += wv.x * hv.x + wv.y * hv.y + wv.z * hv.z + wv.w * hv.w;
                }
            }
        }
    }
    if (active) {
        const float bias = fcb[o];
        #pragma unroll
        for (int bb = 0; bb < 4; ++bb) {
            out[(size_t)(b0 + tb * 4 + bb) * C_DIM + o] = acc[bb] + bias;
        }
    }
}

extern "C" void kernel_launch(void* const* d_in, const int* in_sizes, int n_in,
                              void* d_out, int out_size, void* d_ws, size_t ws_size,
                              hipStream_t stream)
{
    const float* x   = (const float*)d_in[0];
    const float* Wih = (const float*)d_in[1];
    const float* Whh = (const float*)d_in[2];
    const float* bih = (const float*)d_in[3];
    const float* bhh = (const float*)d_in[4];
    const float* fcW = (const float*)d_in[5];
    const float* fcb = (const float*)d_in[6];
    float* out = (float*)d_out;

    char* ws = (char*)d_ws;
    unsigned short* Wc  = (unsigned short*)(ws + 0);         // 10,485,760 B
    unsigned short* xbf = (unsigned short*)(ws + 10485760);  // 33,554,432 B
    float* biasc        = (float*)(ws + 44040192);           //     16,384 B
    unsigned short* hb0 = (unsigned short*)(ws + 44056576);  //    262,144 B
    unsigned short* hb1 = (unsigned short*)(ws + 44318720);  //    262,144 B
    float* hf32         = (float*)(ws + 44580864);           //    524,288 B
    // total ws use: 45,105,152 B (identical to the proven layout)
    unsigned* bar       = (unsigned*)d_out;  // 16 KB of d_out (512,000 B);
                                             // fc_kernel overwrites it last.

    hipLaunchKernelGGL(prep_kernel, dim3(1024), dim3(256), 0, stream,
                       x, Wih, Whh, bih, bhh, Wc, xbf, biasc, hb0, bar);

    hipLaunchKernelGGL(lstm_grid, dim3(256), dim3(256), 0, stream,
                       Wc, xbf, biasc, hb0, hb1, hf32, bar);

    hipLaunchKernelGGL(fc_kernel, dim3(8, 16), dim3(256), 0, stream,
                       hf32, fcW, fcb, out);
}